// Round 1
// baseline (7371.200 us; speedup 1.0000x reference)
//
#include <hip/hip_runtime.h>
#include <stdint.h>

typedef short bf16x8 __attribute__((ext_vector_type(8)));
typedef float f32x4 __attribute__((ext_vector_type(4)));
typedef unsigned short u16;

#define ITERS 50
#define BETA_F 5.0f

// ws layout (float offsets)
#define WS_SUPSUM 0       // 1024: per-class support sums [16][64]
#define WS_COUNTS 1024    // 16
#define WS_CENT   1040    // 1024: centroids [16][64]
#define WS_CSQ    2064    // 16: |centroid|^2
#define WS_ACC    2080    // 8 replicas x (1024 num + 16 den)
#define WS_CORR   10400   // 1: correct-count
#define WS_QB_OFF 10432   // bf16 query cache starts here (u16*)

__device__ __forceinline__ u16 f2bf(float x) {
  union { float f; uint32_t u; } v; v.f = x;
  uint32_t r = (v.u + 0x7FFFu + ((v.u >> 16) & 1u)) >> 16;
  return (u16)r;
}
__device__ __forceinline__ float bf2f(u16 b) {
  union { float f; uint32_t u; } v; v.u = ((uint32_t)b) << 16;
  return v.f;
}
__device__ __forceinline__ uint32_t fkey(float f) {
  union { float f; uint32_t u; } v; v.f = f;
  return (v.u & 0x80000000u) ? ~v.u : (v.u | 0x80000000u);
}

// ---------- init: support sums, counts, initial centroids, zero accumulators ----------
__global__ __launch_bounds__(1024) void init_kernel(const float* __restrict__ sup,
                                                    const int* __restrict__ slab,
                                                    int NS, float* __restrict__ ws) {
  const int tid = threadIdx.x;
  const int c = tid >> 6, j = tid & 63;
  float s = 0.f; int cnt = 0;
  for (int i = 0; i < NS; ++i) {
    int lbl = slab[i];
    float v = sup[i * 64 + j];
    if (lbl == c) { s += v; cnt++; }
  }
  ws[WS_SUPSUM + tid] = s;
  if (j == 0) ws[WS_COUNTS + c] = (float)cnt;
  ws[WS_CENT + tid] = s / (float)cnt;
  for (int i = tid; i < 8 * 1040; i += 1024) ws[WS_ACC + i] = 0.f;
  if (tid == 0) ws[WS_CORR] = 0.f;
  __syncthreads();
  if (j == 0) {
    float sq = 0.f;
    for (int k = 0; k < 64; ++k) { float v = ws[WS_CENT + c * 64 + k]; sq += v * v; }
    ws[WS_CSQ + c] = sq;
  }
}

// ---------- fp32 -> bf16 query cache ----------
__global__ __launch_bounds__(256) void convert_kernel(const float* __restrict__ qf,
                                                      u16* __restrict__ qb, int n) {
  const int start = blockIdx.x * 256 + threadIdx.x;
  const int stride = gridDim.x * 256;
  const float4* in = (const float4*)qf;
  uint2* out = (uint2*)qb;
  for (int k = start; k < (n >> 2); k += stride) {
    float4 v = in[k];
    uint32_t p0 = (uint32_t)f2bf(v.x) | ((uint32_t)f2bf(v.y) << 16);
    uint32_t p1 = (uint32_t)f2bf(v.z) | ((uint32_t)f2bf(v.w) << 16);
    out[k] = make_uint2(p0, p1);
  }
}

// ---------- one soft-assignment pass: scores -> softmax -> W^T@Q accumulate ----------
template <bool SRC_BF16>
__global__ __launch_bounds__(256) void pass_kernel(const float* __restrict__ qf,
                                                   const u16* __restrict__ qb,
                                                   int NQ, float* __restrict__ ws) {
  __shared__ __attribute__((aligned(16))) u16 w_lds[4][16][32];   // [wave][class][query]
  __shared__ __attribute__((aligned(16))) u16 qt_lds[4][64][32];  // [wave][dim][query]
  __shared__ float redden[16];

  const int tid = threadIdx.x;
  const int lane = tid & 63;
  const int wv = tid >> 6;
  const int c = lane & 15;   // class column (GEMM1 B / GEMM2 A m-index)
  const int g = lane >> 4;   // 0..3

  // centroid B-fragments in registers: B[n=class=c][k]; chunk0 dims g*8+j, chunk1 dims 32+g*8+j
  const float* cent = ws + WS_CENT;
  bf16x8 bc0, bc1;
#pragma unroll
  for (int j = 0; j < 8; ++j) {
    bc0[j] = (short)f2bf(cent[c * 64 + g * 8 + j]);
    bc1[j] = (short)f2bf(cent[c * 64 + 32 + g * 8 + j]);
  }
  const float csq = ws[WS_CSQ + c];

  f32x4 acc[4];
#pragma unroll
  for (int nt = 0; nt < 4; ++nt) acc[nt] = (f32x4){0.f, 0.f, 0.f, 0.f};
  float denacc = 0.f;

  const int wave_id = blockIdx.x * 4 + wv;
  const int nwaves = gridDim.x * 4;
  const int ntiles = NQ >> 5;  // 32 queries per wave-tile

  for (int tile = wave_id; tile < ntiles; tile += nwaves) {
    const int qbase = tile << 5;
#pragma unroll
    for (int st = 0; st < 2; ++st) {
      const int q = qbase + st * 16 + c;  // A-frag: m = lane&15 = query
      bf16x8 a0, a1;
      if (SRC_BF16) {
        const u16* qrow = qb + (size_t)q * 64;
        a0 = *(const bf16x8*)(qrow + g * 8);
        a1 = *(const bf16x8*)(qrow + 32 + g * 8);
      } else {
        const float* qrow = qf + (size_t)q * 64;
#pragma unroll
        for (int j = 0; j < 8; ++j) {
          a0[j] = (short)f2bf(qrow[g * 8 + j]);
          a1[j] = (short)f2bf(qrow[32 + g * 8 + j]);
        }
      }
      f32x4 sc = (f32x4){0.f, 0.f, 0.f, 0.f};
      sc = __builtin_amdgcn_mfma_f32_16x16x32_bf16(a0, bc0, sc, 0, 0, 0);
      sc = __builtin_amdgcn_mfma_f32_16x16x32_bf16(a1, bc1, sc, 0, 0, 0);
      // D layout: this lane holds queries (st*16 + g*4 + r), class c.
      // softmax over classes == over the 16-lane group (qsq cancels)
      u16 wq[4];
#pragma unroll
      for (int r = 0; r < 4; ++r) {
        float s = BETA_F * (2.f * sc[r] - csq);
        float m = s;
#pragma unroll
        for (int msk = 1; msk < 16; msk <<= 1) m = fmaxf(m, __shfl_xor(m, msk));
        float e = __expf(s - m);
        float sum = e;
#pragma unroll
        for (int msk = 1; msk < 16; msk <<= 1) sum += __shfl_xor(sum, msk);
        float w = e / sum;
        wq[r] = f2bf(w);
        denacc += bf2f(wq[r]);  // self-consistent with quantized num
      }
      uint32_t lo = (uint32_t)wq[0] | ((uint32_t)wq[1] << 16);
      uint32_t hi = (uint32_t)wq[2] | ((uint32_t)wq[3] << 16);
      *(uint2*)&w_lds[wv][c][st * 16 + g * 4] = make_uint2(lo, hi);
      // transpose Q frag into qt_lds (this lane owns query st*16+c, dims g*8+j / 32+g*8+j)
#pragma unroll
      for (int j = 0; j < 8; ++j) {
        qt_lds[wv][g * 8 + j][st * 16 + c] = (u16)a0[j];
        qt_lds[wv][32 + g * 8 + j][st * 16 + c] = (u16)a1[j];
      }
    }
    // GEMM2: OUT[16 class][64 dim] += W^T @ Q over K=32 queries (wave-private LDS, no barrier)
    bf16x8 aw = *(const bf16x8*)&w_lds[wv][c][g * 8];
#pragma unroll
    for (int nt = 0; nt < 4; ++nt) {
      bf16x8 bq = *(const bf16x8*)&qt_lds[wv][nt * 16 + c][g * 8];
      acc[nt] = __builtin_amdgcn_mfma_f32_16x16x32_bf16(aw, bq, acc[nt], 0, 0, 0);
    }
  }

  // block reduction (reuse wave-0 qt region as 1024-float scratch), then replicated atomics
  __syncthreads();
  float* red = (float*)&qt_lds[0][0][0];
  for (int i = tid; i < 1024; i += 256) red[i] = 0.f;
  if (tid < 16) redden[tid] = 0.f;
  __syncthreads();
#pragma unroll
  for (int nt = 0; nt < 4; ++nt)
#pragma unroll
    for (int r = 0; r < 4; ++r)
      atomicAdd(&red[(g * 4 + r) * 64 + nt * 16 + c], acc[nt][r]);
  atomicAdd(&redden[c], denacc);
  __syncthreads();
  float* accn = ws + WS_ACC + (size_t)(blockIdx.x & 7) * 1040;
  for (int i = tid; i < 1024; i += 256) atomicAdd(&accn[i], red[i]);
  if (tid < 16) atomicAdd(&accn[1024 + tid], redden[tid]);
}

// ---------- centroid update ----------
__global__ __launch_bounds__(1024) void update_kernel(float* __restrict__ ws) {
  const int tid = threadIdx.x;
  const int c = tid >> 6;
  float num = ws[WS_SUPSUM + tid];
  float den = ws[WS_COUNTS + c];
#pragma unroll
  for (int rep = 0; rep < 8; ++rep) {
    num += ws[WS_ACC + rep * 1040 + tid];
    den += ws[WS_ACC + rep * 1040 + 1024 + c];
  }
  ws[WS_CENT + tid] = num / den;
  for (int i = tid; i < 8 * 1040; i += 1024) ws[WS_ACC + i] = 0.f;
  __syncthreads();
  if ((tid & 63) == 0) {
    float sq = 0.f;
    for (int k = 0; k < 64; ++k) { float v = ws[WS_CENT + c * 64 + k]; sq += v * v; }
    ws[WS_CSQ + c] = sq;
  }
}

// ---------- final argmin + accuracy count ----------
template <bool SRC_BF16>
__global__ __launch_bounds__(256) void final_kernel(const float* __restrict__ qf,
                                                    const u16* __restrict__ qb,
                                                    const int* __restrict__ qlab,
                                                    int NQ, float* __restrict__ ws) {
  const int tid = threadIdx.x;
  const int lane = tid & 63;
  const int wv = tid >> 6;
  const int c = lane & 15;
  const int g = lane >> 4;

  const float* cent = ws + WS_CENT;
  bf16x8 bc0, bc1;
#pragma unroll
  for (int j = 0; j < 8; ++j) {
    bc0[j] = (short)f2bf(cent[c * 64 + g * 8 + j]);
    bc1[j] = (short)f2bf(cent[c * 64 + 32 + g * 8 + j]);
  }
  const float csq = ws[WS_CSQ + c];

  int cnt = 0;
  const int wave_id = blockIdx.x * 4 + wv;
  const int nwaves = gridDim.x * 4;
  const int ntiles = NQ >> 4;  // 16 queries per tile

  for (int tile = wave_id; tile < ntiles; tile += nwaves) {
    const int qbase = tile << 4;
    const int q = qbase + c;
    bf16x8 a0, a1;
    if (SRC_BF16) {
      const u16* qrow = qb + (size_t)q * 64;
      a0 = *(const bf16x8*)(qrow + g * 8);
      a1 = *(const bf16x8*)(qrow + 32 + g * 8);
    } else {
      const float* qrow = qf + (size_t)q * 64;
#pragma unroll
      for (int j = 0; j < 8; ++j) {
        a0[j] = (short)f2bf(qrow[g * 8 + j]);
        a1[j] = (short)f2bf(qrow[32 + g * 8 + j]);
      }
    }
    f32x4 sc = (f32x4){0.f, 0.f, 0.f, 0.f};
    sc = __builtin_amdgcn_mfma_f32_16x16x32_bf16(a0, bc0, sc, 0, 0, 0);
    sc = __builtin_amdgcn_mfma_f32_16x16x32_bf16(a1, bc1, sc, 0, 0, 0);
#pragma unroll
    for (int r = 0; r < 4; ++r) {
      float val = 2.f * sc[r] - csq;  // argmax(val) == argmin(d2); beta>0 monotone
      unsigned long long p = ((unsigned long long)fkey(val) << 32) | (unsigned long long)(15 - c);
#pragma unroll
      for (int msk = 1; msk < 16; msk <<= 1) {
        unsigned long long o = __shfl_xor(p, msk);
        p = (o > p) ? o : p;
      }
      int pred = 15 - (int)(p & 0xFFFFull);
      if (c == 0) cnt += (qlab[qbase + g * 4 + r] == pred) ? 1 : 0;
    }
  }
#pragma unroll
  for (int msk = 1; msk < 64; msk <<= 1) cnt += __shfl_xor(cnt, msk);
  if (lane == 0) atomicAdd(&ws[WS_CORR], (float)cnt);
}

__global__ void finalize_kernel(const float* __restrict__ ws, float* __restrict__ out, float inv) {
  out[0] = ws[WS_CORR] * inv;
}

extern "C" void kernel_launch(void* const* d_in, const int* in_sizes, int n_in,
                              void* d_out, int out_size, void* d_ws, size_t ws_size,
                              hipStream_t stream) {
  const float* sup = (const float*)d_in[0];
  const float* qf  = (const float*)d_in[1];
  const int* slab  = (const int*)d_in[2];
  const int* qlab  = (const int*)d_in[3];
  float* ws = (float*)d_ws;
  float* out = (float*)d_out;
  const int NS = in_sizes[0] / 64;
  const int NQ = in_sizes[1] / 64;
  u16* qb = (u16*)(ws + WS_QB_OFF);
  const size_t need = (size_t)WS_QB_OFF * 4 + (size_t)NQ * 64 * 2;
  const bool use_bf = (ws_size >= need);

  init_kernel<<<1, 1024, 0, stream>>>(sup, slab, NS, ws);
  if (use_bf) convert_kernel<<<4096, 256, 0, stream>>>(qf, qb, NQ * 64);
  for (int it = 0; it < ITERS; ++it) {
    if (use_bf) pass_kernel<true><<<2048, 256, 0, stream>>>(qf, qb, NQ, ws);
    else        pass_kernel<false><<<2048, 256, 0, stream>>>(qf, qb, NQ, ws);
    update_kernel<<<1, 1024, 0, stream>>>(ws);
  }
  if (use_bf) final_kernel<true><<<2048, 256, 0, stream>>>(qf, qb, qlab, NQ, ws);
  else        final_kernel<false><<<2048, 256, 0, stream>>>(qf, qb, qlab, NQ, ws);
  finalize_kernel<<<1, 1, 0, stream>>>(ws, out, 1.0f / (float)NQ);
}

// Round 2
// 5806.974 us; speedup vs baseline: 1.2694x; 1.2694x over previous
//
#include <hip/hip_runtime.h>
#include <stdint.h>

typedef short bf16x8 __attribute__((ext_vector_type(8)));
typedef float f32x4 __attribute__((ext_vector_type(4)));
typedef uint32_t u32x4 __attribute__((ext_vector_type(4)));
typedef unsigned short u16;

#define ITERS 50
#define BETA_F 5.0f

// ws layout (float offsets)
#define WS_SUPSUM 0       // 1024: per-class support sums [16][64]
#define WS_COUNTS 1024    // 16
#define WS_CENT   1040    // 1024: centroids [16][64]
#define WS_CSQ    2064    // 16: |centroid|^2
#define WS_ACC    2080    // 8 replicas x (1024 num + 16 den)
#define WS_CORR   10400   // 1: correct-count
#define WS_QB_OFF 10432   // bf16 query cache starts here (u16*)

__device__ __forceinline__ u16 f2bf(float x) {
  union { float f; uint32_t u; } v; v.f = x;
  uint32_t r = (v.u + 0x7FFFu + ((v.u >> 16) & 1u)) >> 16;
  return (u16)r;
}
__device__ __forceinline__ float bf2f(u16 b) {
  union { float f; uint32_t u; } v; v.u = ((uint32_t)b) << 16;
  return v.f;
}
__device__ __forceinline__ uint32_t fkey(float f) {
  union { float f; uint32_t u; } v; v.f = f;
  return (v.u & 0x80000000u) ? ~v.u : (v.u | 0x80000000u);
}

// ---- DPP cross-lane (VALU pipe, not LDS) ----
// 0xB1 = quad_perm(1,0,3,2) xor1; 0x4E = quad_perm(2,3,0,1) xor2;
// 0x141 = row_half_mirror (pairs quads within 8); 0x140 = row_mirror (pairs 8s within 16)
template <int CTRL>
__device__ __forceinline__ float dppf(float x) {
  int i = __builtin_bit_cast(int, x);
  int r = __builtin_amdgcn_update_dpp(i, i, CTRL, 0xF, 0xF, false);
  return __builtin_bit_cast(float, r);
}
template <int CTRL>
__device__ __forceinline__ uint32_t dppu(uint32_t x) {
  int r = __builtin_amdgcn_update_dpp((int)x, (int)x, CTRL, 0xF, 0xF, false);
  return (uint32_t)r;
}
__device__ __forceinline__ float rmax16(float x) {
  x = fmaxf(x, dppf<0xB1>(x));
  x = fmaxf(x, dppf<0x4E>(x));
  x = fmaxf(x, dppf<0x141>(x));
  x = fmaxf(x, dppf<0x140>(x));
  return x;
}
__device__ __forceinline__ float rsum16(float x) {
  x += dppf<0xB1>(x);
  x += dppf<0x4E>(x);
  x += dppf<0x141>(x);
  x += dppf<0x140>(x);
  return x;
}
__device__ __forceinline__ uint32_t rumax16(uint32_t x) {
  uint32_t t;
  t = dppu<0xB1>(x);  x = (t > x) ? t : x;
  t = dppu<0x4E>(x);  x = (t > x) ? t : x;
  t = dppu<0x141>(x); x = (t > x) ? t : x;
  t = dppu<0x140>(x); x = (t > x) ? t : x;
  return x;
}

// ---------- init: support sums, counts, initial centroids, zero accumulators ----------
__global__ __launch_bounds__(1024) void init_kernel(const float* __restrict__ sup,
                                                    const int* __restrict__ slab,
                                                    int NS, float* __restrict__ ws) {
  const int tid = threadIdx.x;
  const int c = tid >> 6, j = tid & 63;
  float s = 0.f; int cnt = 0;
  for (int i = 0; i < NS; ++i) {
    int lbl = slab[i];
    float v = sup[i * 64 + j];
    if (lbl == c) { s += v; cnt++; }
  }
  ws[WS_SUPSUM + tid] = s;
  if (j == 0) ws[WS_COUNTS + c] = (float)cnt;
  ws[WS_CENT + tid] = s / (float)cnt;
  for (int i = tid; i < 8 * 1040; i += 1024) ws[WS_ACC + i] = 0.f;
  if (tid == 0) ws[WS_CORR] = 0.f;
  __syncthreads();
  if (j == 0) {
    float sq = 0.f;
    for (int k = 0; k < 64; ++k) { float v = ws[WS_CENT + c * 64 + k]; sq += v * v; }
    ws[WS_CSQ + c] = sq;
  }
}

// ---------- fp32 -> bf16 query cache ----------
__global__ __launch_bounds__(256) void convert_kernel(const float* __restrict__ qf,
                                                      u16* __restrict__ qb, int n) {
  const int start = blockIdx.x * 256 + threadIdx.x;
  const int stride = gridDim.x * 256;
  const float4* in = (const float4*)qf;
  uint2* out = (uint2*)qb;
  for (int k = start; k < (n >> 2); k += stride) {
    float4 v = in[k];
    uint32_t p0 = (uint32_t)f2bf(v.x) | ((uint32_t)f2bf(v.y) << 16);
    uint32_t p1 = (uint32_t)f2bf(v.z) | ((uint32_t)f2bf(v.w) << 16);
    out[k] = make_uint2(p0, p1);
  }
}

// ---------- one soft-assignment pass: scores -> softmax -> W^T@Q accumulate ----------
template <bool SRC_BF16>
__global__ __launch_bounds__(256, 4) void pass_kernel(const float* __restrict__ qf,
                                                      const u16* __restrict__ qb,
                                                      int NQ, float* __restrict__ ws) {
  // qt_w[wave][dim][word-col]: word = 2 bf16 = (query 2t, query 2t+1) of one dim,
  // word-col swizzled with ^(g<<2) to break bank conflicts (undone at read).
  __shared__ __attribute__((aligned(16))) uint32_t qt_w[4][64][16];
  __shared__ __attribute__((aligned(16))) u16 w_lds[4][16][32];   // [wave][class][query]
  __shared__ float redden[16];

  const int tid = threadIdx.x;
  const int lane = tid & 63;
  const int wv = tid >> 6;
  const int c = lane & 15;   // class col (GEMM1 B / GEMM2 A m-index)
  const int g = lane >> 4;   // 0..3

  const float* cent = ws + WS_CENT;
  bf16x8 bc0, bc1;
#pragma unroll
  for (int j = 0; j < 8; ++j) {
    bc0[j] = (short)f2bf(cent[c * 64 + g * 8 + j]);
    bc1[j] = (short)f2bf(cent[c * 64 + 32 + g * 8 + j]);
  }
  const float csq = ws[WS_CSQ + c];

  f32x4 acc[4];
#pragma unroll
  for (int nt = 0; nt < 4; ++nt) acc[nt] = (f32x4){0.f, 0.f, 0.f, 0.f};
  float denacc = 0.f;

  const uint32_t psel = (c & 1) ? 0x03020706u : 0x05040100u;

  const int wave_id = blockIdx.x * 4 + wv;
  const int nwaves = gridDim.x * 4;
  const int ntiles = NQ >> 5;  // 32 queries per wave-tile

  for (int tile = wave_id; tile < ntiles; tile += nwaves) {
    const int qbase = tile << 5;
#pragma unroll
    for (int st = 0; st < 2; ++st) {
      const int q = qbase + st * 16 + c;  // A-frag: m = lane&15 = query
      bf16x8 a0, a1;
      if (SRC_BF16) {
        const u16* qrow = qb + (size_t)q * 64;
        a0 = *(const bf16x8*)(qrow + g * 8);
        a1 = *(const bf16x8*)(qrow + 32 + g * 8);
      } else {
        const float* qrow = qf + (size_t)q * 64;
#pragma unroll
        for (int j = 0; j < 8; ++j) {
          a0[j] = (short)f2bf(qrow[g * 8 + j]);
          a1[j] = (short)f2bf(qrow[32 + g * 8 + j]);
        }
      }
      f32x4 sc = (f32x4){0.f, 0.f, 0.f, 0.f};
      sc = __builtin_amdgcn_mfma_f32_16x16x32_bf16(a0, bc0, sc, 0, 0, 0);
      sc = __builtin_amdgcn_mfma_f32_16x16x32_bf16(a1, bc1, sc, 0, 0, 0);
      // D layout: lane holds queries (st*16 + g*4 + r), class c.
      // softmax over classes == across the 16-lane row (q_sq cancels) — DPP, VALU pipe
      u16 wq[4];
#pragma unroll
      for (int r = 0; r < 4; ++r) {
        float sv = BETA_F * (2.f * sc[r] - csq);
        float m = rmax16(sv);
        float e = __expf(sv - m);
        float sum = rsum16(e);
        float w = e * __builtin_amdgcn_rcpf(sum);
        wq[r] = f2bf(w);
        denacc += bf2f(wq[r]);  // self-consistent with quantized num
      }
      {
        uint32_t lo = (uint32_t)wq[0] | ((uint32_t)wq[1] << 16);
        uint32_t hi = (uint32_t)wq[2] | ((uint32_t)wq[3] << 16);
        *(uint2*)&w_lds[wv][c][st * 16 + g * 4] = make_uint2(lo, hi);
      }
      // transpose Q frag into qt_w: DPP xor1 + v_perm builds (2-query, 1-dim) words;
      // even lane writes dim g*8+2p, odd lane dim g*8+2p+1. 2-way banked (free).
      const int drow = g * 8 + (c & 1);
      const int wcol = ((st << 3) + (c >> 1)) ^ (g << 2);
      u32x4 ua = __builtin_bit_cast(u32x4, a0);
      u32x4 ub = __builtin_bit_cast(u32x4, a1);
#pragma unroll
      for (int p = 0; p < 4; ++p) {
        uint32_t m0 = ua[p];
        uint32_t n0 = (uint32_t)__builtin_amdgcn_update_dpp((int)m0, (int)m0, 0xB1, 0xF, 0xF, false);
        qt_w[wv][drow + 2 * p][wcol] = __builtin_amdgcn_perm(n0, m0, psel);
        uint32_t m1 = ub[p];
        uint32_t n1 = (uint32_t)__builtin_amdgcn_update_dpp((int)m1, (int)m1, 0xB1, 0xF, 0xF, false);
        qt_w[wv][32 + drow + 2 * p][wcol] = __builtin_amdgcn_perm(n1, m1, psel);
      }
    }
    // GEMM2: OUT[16 class][64 dim] += W^T @ Q over K=32 queries (wave-private, no barrier)
    bf16x8 aw = *(const bf16x8*)&w_lds[wv][c][g * 8];
#pragma unroll
    for (int nt = 0; nt < 4; ++nt) {
      const int K = ((nt << 1) + (c >> 3)) & 3;
      bf16x8 bq = *(const bf16x8*)&qt_w[wv][nt * 16 + c][(g ^ K) << 2];
      acc[nt] = __builtin_amdgcn_mfma_f32_16x16x32_bf16(aw, bq, acc[nt], 0, 0, 0);
    }
  }

  // block reduction (reuse wave-0 qt region as 1024-float scratch), then replicated atomics
  __syncthreads();
  float* red = (float*)&qt_w[0][0][0];
  for (int i = tid; i < 1024; i += 256) red[i] = 0.f;
  if (tid < 16) redden[tid] = 0.f;
  __syncthreads();
#pragma unroll
  for (int nt = 0; nt < 4; ++nt)
#pragma unroll
    for (int r = 0; r < 4; ++r)
      atomicAdd(&red[(g * 4 + r) * 64 + nt * 16 + c], acc[nt][r]);
  atomicAdd(&redden[c], denacc);
  __syncthreads();
  float* accn = ws + WS_ACC + (size_t)(blockIdx.x & 7) * 1040;
  for (int i = tid; i < 1024; i += 256) atomicAdd(&accn[i], red[i]);
  if (tid < 16) atomicAdd(&accn[1024 + tid], redden[tid]);
}

// ---------- centroid update ----------
__global__ __launch_bounds__(1024) void update_kernel(float* __restrict__ ws) {
  const int tid = threadIdx.x;
  const int c = tid >> 6;
  float num = ws[WS_SUPSUM + tid];
  float den = ws[WS_COUNTS + c];
#pragma unroll
  for (int rep = 0; rep < 8; ++rep) {
    num += ws[WS_ACC + rep * 1040 + tid];
    den += ws[WS_ACC + rep * 1040 + 1024 + c];
  }
  ws[WS_CENT + tid] = num / den;
  for (int i = tid; i < 8 * 1040; i += 1024) ws[WS_ACC + i] = 0.f;
  __syncthreads();
  if ((tid & 63) == 0) {
    float sq = 0.f;
    for (int k = 0; k < 64; ++k) { float v = ws[WS_CENT + c * 64 + k]; sq += v * v; }
    ws[WS_CSQ + c] = sq;
  }
}

// ---------- final argmin + accuracy count ----------
template <bool SRC_BF16>
__global__ __launch_bounds__(256, 4) void final_kernel(const float* __restrict__ qf,
                                                       const u16* __restrict__ qb,
                                                       const int* __restrict__ qlab,
                                                       int NQ, float* __restrict__ ws) {
  const int tid = threadIdx.x;
  const int lane = tid & 63;
  const int c = lane & 15;
  const int g = lane >> 4;

  const float* cent = ws + WS_CENT;
  bf16x8 bc0, bc1;
#pragma unroll
  for (int j = 0; j < 8; ++j) {
    bc0[j] = (short)f2bf(cent[c * 64 + g * 8 + j]);
    bc1[j] = (short)f2bf(cent[c * 64 + 32 + g * 8 + j]);
  }
  const float csq = ws[WS_CSQ + c];

  int cnt = 0;
  const int wave_id = blockIdx.x * 4 + (tid >> 6);
  const int nwaves = gridDim.x * 4;
  const int ntiles = NQ >> 4;  // 16 queries per tile

  for (int tile = wave_id; tile < ntiles; tile += nwaves) {
    const int qbase = tile << 4;
    const int q = qbase + c;
    bf16x8 a0, a1;
    if (SRC_BF16) {
      const u16* qrow = qb + (size_t)q * 64;
      a0 = *(const bf16x8*)(qrow + g * 8);
      a1 = *(const bf16x8*)(qrow + 32 + g * 8);
    } else {
      const float* qrow = qf + (size_t)q * 64;
#pragma unroll
      for (int j = 0; j < 8; ++j) {
        a0[j] = (short)f2bf(qrow[g * 8 + j]);
        a1[j] = (short)f2bf(qrow[32 + g * 8 + j]);
      }
    }
    f32x4 sc = (f32x4){0.f, 0.f, 0.f, 0.f};
    sc = __builtin_amdgcn_mfma_f32_16x16x32_bf16(a0, bc0, sc, 0, 0, 0);
    sc = __builtin_amdgcn_mfma_f32_16x16x32_bf16(a1, bc1, sc, 0, 0, 0);
#pragma unroll
    for (int r = 0; r < 4; ++r) {
      float val = 2.f * sc[r] - csq;  // argmax(val) == argmin(d2)
      // pack class in low 4 bits (15-c: ties -> smallest class, matching argmin)
      uint32_t key = (fkey(val) & 0xFFFFFFF0u) | (uint32_t)(15 - c);
      key = rumax16(key);
      int pred = 15 - (int)(key & 15u);
      if (c == 0) cnt += (qlab[qbase + g * 4 + r] == pred) ? 1 : 0;
    }
  }
#pragma unroll
  for (int msk = 1; msk < 64; msk <<= 1) cnt += __shfl_xor(cnt, msk);
  if (lane == 0) atomicAdd(&ws[WS_CORR], (float)cnt);
}

__global__ void finalize_kernel(const float* __restrict__ ws, float* __restrict__ out, float inv) {
  out[0] = ws[WS_CORR] * inv;
}

extern "C" void kernel_launch(void* const* d_in, const int* in_sizes, int n_in,
                              void* d_out, int out_size, void* d_ws, size_t ws_size,
                              hipStream_t stream) {
  const float* sup = (const float*)d_in[0];
  const float* qf  = (const float*)d_in[1];
  const int* slab  = (const int*)d_in[2];
  const int* qlab  = (const int*)d_in[3];
  float* ws = (float*)d_ws;
  float* out = (float*)d_out;
  const int NS = in_sizes[0] / 64;
  const int NQ = in_sizes[1] / 64;
  u16* qb = (u16*)(ws + WS_QB_OFF);
  const size_t need = (size_t)WS_QB_OFF * 4 + (size_t)NQ * 64 * 2;
  const bool use_bf = (ws_size >= need);

  init_kernel<<<1, 1024, 0, stream>>>(sup, slab, NS, ws);
  if (use_bf) convert_kernel<<<4096, 256, 0, stream>>>(qf, qb, NQ * 64);
  for (int it = 0; it < ITERS; ++it) {
    if (use_bf) pass_kernel<true><<<2048, 256, 0, stream>>>(qf, qb, NQ, ws);
    else        pass_kernel<false><<<2048, 256, 0, stream>>>(qf, qb, NQ, ws);
    update_kernel<<<1, 1024, 0, stream>>>(ws);
  }
  if (use_bf) final_kernel<true><<<2048, 256, 0, stream>>>(qf, qb, qlab, NQ, ws);
  else        final_kernel<false><<<2048, 256, 0, stream>>>(qf, qb, qlab, NQ, ws);
  finalize_kernel<<<1, 1, 0, stream>>>(ws, out, 1.0f / (float)NQ);
}